// Round 2
// 324.083 us; speedup vs baseline: 1.0311x; 1.0311x over previous
//
#include <hip/hip_runtime.h>
#include <math.h>

#define LOG2E 1.44269504088896340736f

typedef float f32x4 __attribute__((ext_vector_type(4)));

// Fast sigmoid(-z) = 1 / (1 + exp(z)) using native v_exp_f32 / v_rcp_f32.
// v_exp_f32 handles overflow: z large + -> exp2 -> inf -> rcp -> 0 (correct);
// z large - -> 0 -> rcp(1) = 1 (correct).
__device__ __forceinline__ float sigm_neg(float z) {
    float e = __builtin_amdgcn_exp2f(z * LOG2E);
    return __builtin_amdgcn_rcpf(1.0f + e);
}

__device__ __forceinline__ float rcp_fast(float z) {
    return __builtin_amdgcn_rcpf(z);
}

// spu(z) = z^2 - 0.5 (z>=0) | sigmoid(-z) - 1 (z<0), with sigmoid given
__device__ __forceinline__ float spu_from_sig(float z, float s) {
    return (z >= 0.0f) ? (z * z - 0.5f) : (s - 1.0f);
}

__device__ __forceinline__ void spu_elem(float x, float l, float u,
                                         float& xo, float& lo, float& uo) {
    // p = clip(u - (|l| + |u|)/2, l, u)
    float p = u - (fabsf(l) + fabsf(u)) * 0.5f;
    p = fminf(fmaxf(p, l), u);

    // 4 native exps total (l, u, p, x); sigmoid of p shared by spu & dspu
    float sig_l = sigm_neg(l);
    float sig_u = sigm_neg(u);
    float sig_p = sigm_neg(p);
    float sig_x = sigm_neg(x);

    float sl = spu_from_sig(l, sig_l);
    float su = spu_from_sig(u, sig_u);
    float sp = spu_from_sig(p, sig_p);

    // chord through (l, sl) and (u, su)
    float chord_slope = (su - sl) * rcp_fast((u != l) ? (u - l) : 1.0f);
    float chord_int   = sl - chord_slope * l;
    // tangent at p: dspu(p) = 2p (p>=0) | -s(1-s) (p<0)
    float tan_slope = (p >= 0.0f) ? (2.0f * p) : (-sig_p * (1.0f - sig_p));
    float tan_int   = sp - p * tan_slope;
    // line through (l, sl) and (0, -0.5)
    float zl_slope = (-0.5f - sl) * rcp_fast((l != 0.0f) ? (-l) : 1.0f);
    float zl_int   = -0.5f;

    bool upos = (u > 0.0f);
    bool ppos = (p >= 0.0f);

    float lb_slope = upos ? (ppos ? tan_slope : zl_slope) : chord_slope;
    float lb_int   = upos ? (ppos ? tan_int   : zl_int  ) : chord_int;
    float ub_slope = upos ? chord_slope : tan_slope;
    float ub_int   = upos ? chord_int   : tan_int;

    lo = lb_int + ((lb_slope > 0.0f) ? l : u) * lb_slope;
    uo = ub_int + ((ub_slope > 0.0f) ? u : l) * ub_slope;
    xo = spu_from_sig(x, sig_x);
}

__device__ __forceinline__ void spu_vec4(f32x4 xv, f32x4 lv, f32x4 uv,
                                         f32x4& xov, f32x4& lov, f32x4& uov) {
    float a, b, c;
    spu_elem(xv.x, lv.x, uv.x, a, b, c); xov.x = a; lov.x = b; uov.x = c;
    spu_elem(xv.y, lv.y, uv.y, a, b, c); xov.y = a; lov.y = b; uov.y = c;
    spu_elem(xv.z, lv.z, uv.z, a, b, c); xov.z = a; lov.z = b; uov.z = c;
    spu_elem(xv.w, lv.w, uv.w, a, b, c); xov.w = a; lov.w = b; uov.w = c;
}

// 2 x float4 per thread: 6 loads in flight before any compute (MLP),
// nontemporal loads/stores (touch-once stream; don't allocate in L2/L3).
__global__ __launch_bounds__(256) void spu_transformer_kernel(
    const float* __restrict__ x,
    const float* __restrict__ l,
    const float* __restrict__ u,
    float* __restrict__ xo,
    float* __restrict__ lo,
    float* __restrict__ uo,
    int n)
{
    const int n4 = n >> 2;
    const int tid = threadIdx.x;
    const int i0 = blockIdx.x * 512 + tid;   // chunk 0: [block*512, block*512+256)
    const int i1 = i0 + 256;                 // chunk 1: contiguous next 256 float4s

    const f32x4* __restrict__ x4 = (const f32x4*)x;
    const f32x4* __restrict__ l4 = (const f32x4*)l;
    const f32x4* __restrict__ u4 = (const f32x4*)u;
    f32x4* __restrict__ xo4 = (f32x4*)xo;
    f32x4* __restrict__ lo4 = (f32x4*)lo;
    f32x4* __restrict__ uo4 = (f32x4*)uo;

    if (i1 < n4) {
        // fast path (uniform for all full blocks): issue all 6 loads up front
        f32x4 xv0 = __builtin_nontemporal_load(x4 + i0);
        f32x4 lv0 = __builtin_nontemporal_load(l4 + i0);
        f32x4 uv0 = __builtin_nontemporal_load(u4 + i0);
        f32x4 xv1 = __builtin_nontemporal_load(x4 + i1);
        f32x4 lv1 = __builtin_nontemporal_load(l4 + i1);
        f32x4 uv1 = __builtin_nontemporal_load(u4 + i1);

        f32x4 xov, lov, uov;
        spu_vec4(xv0, lv0, uv0, xov, lov, uov);
        __builtin_nontemporal_store(xov, xo4 + i0);
        __builtin_nontemporal_store(lov, lo4 + i0);
        __builtin_nontemporal_store(uov, uo4 + i0);

        spu_vec4(xv1, lv1, uv1, xov, lov, uov);
        __builtin_nontemporal_store(xov, xo4 + i1);
        __builtin_nontemporal_store(lov, lo4 + i1);
        __builtin_nontemporal_store(uov, uo4 + i1);
    } else if (i0 < n4) {
        // boundary block, chunk 0 only
        f32x4 xv0 = __builtin_nontemporal_load(x4 + i0);
        f32x4 lv0 = __builtin_nontemporal_load(l4 + i0);
        f32x4 uv0 = __builtin_nontemporal_load(u4 + i0);
        f32x4 xov, lov, uov;
        spu_vec4(xv0, lv0, uv0, xov, lov, uov);
        __builtin_nontemporal_store(xov, xo4 + i0);
        __builtin_nontemporal_store(lov, lo4 + i0);
        __builtin_nontemporal_store(uov, uo4 + i0);
    }

    // scalar tail (n % 4 != 0 safety; no-op for n = 16M)
    const int tail_start = n4 << 2;
    const int tail_count = n - tail_start;
    if (tail_count > 0) {
        const int gtid = blockIdx.x * 256 + tid;
        if (gtid < tail_count) {
            const int ti = tail_start + gtid;
            float xs, ls, us;
            spu_elem(x[ti], l[ti], u[ti], xs, ls, us);
            xo[ti] = xs;
            lo[ti] = ls;
            uo[ti] = us;
        }
    }
}

extern "C" void kernel_launch(void* const* d_in, const int* in_sizes, int n_in,
                              void* d_out, int out_size, void* d_ws, size_t ws_size,
                              hipStream_t stream) {
    const float* x = (const float*)d_in[0];
    const float* l = (const float*)d_in[1];
    const float* u = (const float*)d_in[2];
    int n = in_sizes[0];

    float* xo = (float*)d_out;          // x_out
    float* lo = (float*)d_out + n;      // l_out
    float* uo = (float*)d_out + 2 * n;  // u_out

    int n4 = n >> 2;
    // 512 float4s per block (2 per thread)
    int grid = (n4 + 511) / 512;
    if (grid < 1) grid = 1;
    spu_transformer_kernel<<<grid, 256, 0, stream>>>(x, l, u, xo, lo, uo, n);
}